// Round 7
// baseline (98.093 us; speedup 1.0000x reference)
//
#include <hip/hip_runtime.h>

#define SDIM 4096
#define DDIM 64
#define HN   16
#define BH   64
#define NC   16

typedef __attribute__((ext_vector_type(8))) short short8;
typedef __attribute__((ext_vector_type(4))) float f32x4;

static __device__ __forceinline__ unsigned short f2bf(float f) {
    unsigned u = __float_as_uint(f);
    return (unsigned short)((u + 0x7FFFu + ((u >> 16) & 1u)) >> 16);   // RNE
}

// ---------------------------------------------------------------------------
// k1 v3 (MFMA + LDS staging): per (bh, 256-row chunk) partial KV[64][64]+ksum.
//  - 64-row K/V tiles staged via coalesced 1KB dwordx4 loads (relu+mask at
//    staging), register-prefetch of tile t+1 under tile t's compute.
//  - Fragments from LDS b32 gathers, pitch 65 -> 2-way banks (free).
//  - Wave w owns e-columns w*16..w*16+15: acc = 4 f32x4, NO cross-wave
//    reduce; ksum-MFMA for d-tile w on wave w (balanced).
// ---------------------------------------------------------------------------
__global__ __launch_bounds__(256, 4) void k1_kv(
    const float* __restrict__ K, const float* __restrict__ V,
    const int* __restrict__ mask,
    float* __restrict__ KVp, float* __restrict__ ksump)
{
    __shared__ float Ks[64 * 65];          // 16.6 KB
    __shared__ float Vs[64 * 65];          // 16.6 KB
    const int tid  = threadIdx.x;
    const int w    = tid >> 6;
    const int l    = tid & 63;
    const int r16  = l & 15;
    const int quad = l >> 4;
    const int bh = blockIdx.x >> 4;        // NC=16
    const int ch = blockIdx.x & 15;
    const int b  = bh >> 4;                // /HN
    const long base = (long)bh * SDIM * DDIM;
    const int s0 = ch * 256;

    const int sr = tid >> 4;               // staging row 0..15 (+i*16)
    const int sc = (tid & 15) << 2;        // staging col 0..60

    // prefetch tile 0 into registers
    float4 kreg[4], vreg[4];
    int    mreg[4];
#pragma unroll
    for (int i = 0; i < 4; ++i) {
        const int r = sr + i * 16;
        kreg[i] = *(const float4*)(K + base + (long)(s0 + r) * DDIM + sc);
        vreg[i] = *(const float4*)(V + base + (long)(s0 + r) * DDIM + sc);
        mreg[i] = mask[b * SDIM + s0 + r];
    }

    f32x4 acc[4];                          // et = w fixed; dt = 0..3
#pragma unroll
    for (int i = 0; i < 4; ++i) acc[i] = (f32x4){0.f, 0.f, 0.f, 0.f};
    f32x4 kacc = (f32x4){0.f, 0.f, 0.f, 0.f};   // ksum tile dt = w
    short8 ones;
#pragma unroll
    for (int j = 0; j < 8; ++j) ones[j] = (short)0x3F80;   // bf16 1.0

    for (int t = 0; t < 4; ++t) {          // 4 tiles of 64 s-rows
        __syncthreads();                   // prev tile's LDS fully consumed
#pragma unroll
        for (int i = 0; i < 4; ++i) {
            const float m = mreg[i] ? 1.f : 0.f;
            float4 kq = kreg[i];
            kq.x = fmaxf(kq.x, 0.f) * m;
            kq.y = fmaxf(kq.y, 0.f) * m;
            kq.z = fmaxf(kq.z, 0.f) * m;
            kq.w = fmaxf(kq.w, 0.f) * m;
            *(float4*)(Ks + (sr + i * 16) * 65 + sc) = kq;
            *(float4*)(Vs + (sr + i * 16) * 65 + sc) = vreg[i];
        }
        __syncthreads();
        if (t < 3) {                       // prefetch next tile (hidden under compute)
            const int r0n = s0 + (t + 1) * 64;
#pragma unroll
            for (int i = 0; i < 4; ++i) {
                const int r = sr + i * 16;
                kreg[i] = *(const float4*)(K + base + (long)(r0n + r) * DDIM + sc);
                vreg[i] = *(const float4*)(V + base + (long)(r0n + r) * DDIM + sc);
                mreg[i] = mask[b * SDIM + r0n + r];
            }
        }
        // compute tile t: k-steps kh=0,1 (32 s each)
#pragma unroll
        for (int kh = 0; kh < 2; ++kh) {
            const int sb = kh * 32 + quad * 8;
            short8 af[4];
#pragma unroll
            for (int dt = 0; dt < 4; ++dt) {
                short8 ta;
#pragma unroll
                for (int j = 0; j < 8; ++j)
                    ta[j] = (short)f2bf(Ks[(sb + j) * 65 + dt * 16 + r16]);
                af[dt] = ta;
            }
            short8 bf;
#pragma unroll
            for (int j = 0; j < 8; ++j)
                bf[j] = (short)f2bf(Vs[(sb + j) * 65 + w * 16 + r16]);
#pragma unroll
            for (int dt = 0; dt < 4; ++dt)
                acc[dt] = __builtin_amdgcn_mfma_f32_16x16x32_bf16(
                    af[dt], bf, acc[dt], 0, 0, 0);
            kacc = __builtin_amdgcn_mfma_f32_16x16x32_bf16(
                af[w], ones, kacc, 0, 0, 0);
        }
    }

    // write partials: wave w owns e-cols w*16..w*16+15 (no cross-wave reduce)
    float* outp = KVp + ((long)bh * NC + ch) * 4096;
#pragma unroll
    for (int dt = 0; dt < 4; ++dt)
#pragma unroll
        for (int r = 0; r < 4; ++r) {
            const int d = dt * 16 + quad * 4 + r;
            outp[d * 64 + w * 16 + r16] = acc[dt][r];
        }
    // ksum rows w*16..w*16+15 (value replicated over r16 cols)
    if (r16 == 0) {
#pragma unroll
        for (int r = 0; r < 4; ++r)
            ksump[((long)bh * NC + ch) * 64 + w * 16 + quad * 4 + r] = kacc[r];
    }
}

// ---------------------------------------------------------------------------
// k2: reduce NC chunk partials -> final KV, ksum. (unchanged)
// ---------------------------------------------------------------------------
__global__ __launch_bounds__(256) void k2_reduce(
    const float* __restrict__ KVp, const float* __restrict__ ksump,
    float* __restrict__ KV, float* __restrict__ ksum)
{
    const int bh = blockIdx.x >> 2;
    const int qt = blockIdx.x & 3;
    const int tid = threadIdx.x;
#pragma unroll
    for (int i = 0; i < 4; ++i) {
        const int idx = qt * 1024 + i * 256 + tid;
        float v = 0.f;
#pragma unroll
        for (int c = 0; c < NC; ++c) v += KVp[((long)bh * NC + c) * 4096 + idx];
        KV[(long)bh * 4096 + idx] = v;
    }
    if (qt == 0 && tid < 64) {
        float v = 0.f;
#pragma unroll
        for (int c = 0; c < NC; ++c) v += ksump[((long)bh * NC + c) * 64 + tid];
        ksum[bh * 64 + tid] = v;
    }
}

// ---------------------------------------------------------------------------
// k3 v4 (MFMA): out = (relu(Q) @ KV_bf16) * (1/norm), norm fp32. (unchanged)
// ---------------------------------------------------------------------------
__global__ __launch_bounds__(256, 4) void k3_out(
    const float* __restrict__ Q, const float* __restrict__ KVm,
    const float* __restrict__ ksum, float* __restrict__ out)
{
    __shared__ float cbuf[4][16 * 68];     // 17.4 KB, per-wave strips
    const int tid  = threadIdx.x;
    const int w    = tid >> 6;
    const int l    = tid & 63;
    const int r16  = l & 15;
    const int quad = l >> 4;
    const int bh    = blockIdx.x >> 4;
    const int strip = blockIdx.x & 15;     // 16 strips x 256 rows

    const float* kvp = KVm + (long)bh * 4096;
    short8 bfrag[2][4];
#pragma unroll
    for (int kh = 0; kh < 2; ++kh)
#pragma unroll
        for (int n = 0; n < 4; ++n) {
            short8 tmp;
#pragma unroll
            for (int j = 0; j < 8; ++j)
                tmp[j] = (short)f2bf(kvp[(kh * 32 + quad * 8 + j) * 64 + n * 16 + r16]);
            bfrag[kh][n] = tmp;
        }
    float ksv[16];
#pragma unroll
    for (int j = 0; j < 8; ++j) {
        ksv[j]     = ksum[bh * 64 + quad * 8 + j];
        ksv[j + 8] = ksum[bh * 64 + 32 + quad * 8 + j];
    }

    const int rowbase = strip * 256 + w * 64;
    const float* qptr = Q + ((long)bh * SDIM + rowbase + r16) * DDIM + quad * 8;
    float* obase = out + ((long)bh * SDIM + rowbase) * DDIM;
    float* cw = &cbuf[w][0];

    f32x4 a0 = *(const f32x4*)(qptr);
    f32x4 a1 = *(const f32x4*)(qptr + 4);
    f32x4 a2 = *(const f32x4*)(qptr + 32);
    f32x4 a3 = *(const f32x4*)(qptr + 36);

    for (int t = 0; t < 4; ++t) {
        f32x4 b0 = a0, b1 = a1, b2 = a2, b3 = a3;
        if (t < 3) {
            const float* qn = qptr + (t + 1) * 16 * DDIM;
            b0 = *(const f32x4*)(qn);
            b1 = *(const f32x4*)(qn + 4);
            b2 = *(const f32x4*)(qn + 32);
            b3 = *(const f32x4*)(qn + 36);
        }
#pragma unroll
        for (int j = 0; j < 4; ++j) {
            a0[j] = fmaxf(a0[j], 0.f); a1[j] = fmaxf(a1[j], 0.f);
            a2[j] = fmaxf(a2[j], 0.f); a3[j] = fmaxf(a3[j], 0.f);
        }
        float p = 0.f;
#pragma unroll
        for (int j = 0; j < 4; ++j) {
            p = fmaf(a0[j], ksv[j],      p);
            p = fmaf(a1[j], ksv[4 + j],  p);
            p = fmaf(a2[j], ksv[8 + j],  p);
            p = fmaf(a3[j], ksv[12 + j], p);
        }
        p += __shfl_xor(p, 16);
        p += __shfl_xor(p, 32);
        const float inv = __builtin_amdgcn_rcpf(p);

        short8 af0, af1;
#pragma unroll
        for (int j = 0; j < 4; ++j) {
            af0[j]     = (short)f2bf(a0[j]);
            af0[4 + j] = (short)f2bf(a1[j]);
            af1[j]     = (short)f2bf(a2[j]);
            af1[4 + j] = (short)f2bf(a3[j]);
        }

        f32x4 acc[4];
#pragma unroll
        for (int n = 0; n < 4; ++n) {
            acc[n] = (f32x4){0.f, 0.f, 0.f, 0.f};
            acc[n] = __builtin_amdgcn_mfma_f32_16x16x32_bf16(af0, bfrag[0][n], acc[n], 0, 0, 0);
            acc[n] = __builtin_amdgcn_mfma_f32_16x16x32_bf16(af1, bfrag[1][n], acc[n], 0, 0, 0);
        }

        float invr[4];
#pragma unroll
        for (int r = 0; r < 4; ++r) invr[r] = __shfl(inv, quad * 4 + r);

#pragma unroll
        for (int n = 0; n < 4; ++n)
#pragma unroll
            for (int r = 0; r < 4; ++r)
                cw[(quad * 4 + r) * 68 + n * 16 + r16] = acc[n][r] * invr[r];

        float* ot = obase + (t * 16) * DDIM;
#pragma unroll
        for (int i = 0; i < 4; ++i) {
            f32x4 v = *(const f32x4*)(cw + (i * 4 + quad) * 68 + r16 * 4);
            *(f32x4*)(ot + (i * 4 + quad) * DDIM + r16 * 4) = v;
        }
        a0 = b0; a1 = b1; a2 = b2; a3 = b3;
    }
}

extern "C" void kernel_launch(void* const* d_in, const int* in_sizes, int n_in,
                              void* d_out, int out_size, void* d_ws, size_t ws_size,
                              hipStream_t stream)
{
    const float* Q    = (const float*)d_in[0];
    const float* K    = (const float*)d_in[1];
    const float* V    = (const float*)d_in[2];
    const int*   mask = (const int*)d_in[3];
    float* out = (float*)d_out;

    // Chunk partials live in d_out (scratch; k3 overwrites all of d_out).
    float* KVp   = out;                                // 16.8 MB scratch
    float* ksump = KVp + (long)BH * NC * 4096;         // 256 KB
    float* KV    = (float*)d_ws;                       // 1 MB
    float* ksum  = KV + (long)BH * 4096;               // 16 KB

    hipLaunchKernelGGL(k1_kv, dim3(BH * NC), dim3(256), 0, stream,
                       K, V, mask, KVp, ksump);
    hipLaunchKernelGGL(k2_reduce, dim3(BH * 4), dim3(256), 0, stream,
                       KVp, ksump, KV, ksum);
    hipLaunchKernelGGL(k3_out, dim3(BH * 16), dim3(256), 0, stream,
                       Q, KV, ksum, out);
}

// Round 8
// 88.658 us; speedup vs baseline: 1.1064x; 1.1064x over previous
//
#include <hip/hip_runtime.h>
#include <hip/hip_bf16.h>

#define SDIM 4096
#define DDIM 64
#define HN   16
#define BH   64
#define NC   16

typedef __attribute__((ext_vector_type(8))) short short8;
typedef __attribute__((ext_vector_type(4))) float f32x4;

static __device__ __forceinline__ short f2bfs(float f) {
    __hip_bfloat16 h = __float2bfloat16(f);      // HW RNE cvt (packable)
    return *reinterpret_cast<short*>(&h);
}

// ---------------------------------------------------------------------------
// k1 v4 (MFMA + swizzled LDS staging): per (bh, 256-row chunk) partial
// KV[64][64] + ksum[64].
//  - 64-row K/V f32 tiles staged with pitch-64 + XOR col swizzle
//    (col ^= ((row>>3)&3)<<4): 16B-aligned b128 staging writes, 2-way
//    (free) fragment gathers. Register-prefetch of tile t+1 under tile t.
//  - Wave w owns e-columns w*16..w*16+15 (no cross-wave reduce).
//  - C-writeout bounced through LDS (reuse Ks) -> 256B-contiguous global
//    stores (fixes round-7's 6x write amplification).
// ---------------------------------------------------------------------------
__global__ __launch_bounds__(256, 4) void k1_kv(
    const float* __restrict__ K, const float* __restrict__ V,
    const int* __restrict__ mask,
    float* __restrict__ KVp, float* __restrict__ ksump)
{
    __shared__ float Ks[4096];             // 16 KB, pitch 64
    __shared__ float Vs[4096];             // 16 KB
    const int tid  = threadIdx.x;
    const int w    = tid >> 6;
    const int l    = tid & 63;
    const int r16  = l & 15;
    const int quad = l >> 4;
    const int bh = blockIdx.x >> 4;        // NC=16
    const int ch = blockIdx.x & 15;
    const int b  = bh >> 4;                // /HN
    const long base = (long)bh * SDIM * DDIM;
    const int s0 = ch * 256;

    const int sr = tid >> 4;               // staging row 0..15 (+i*16)
    const int sc = (tid & 15) << 2;        // staging col 0..60

    // prefetch tile 0 into registers
    float4 kreg[4], vreg[4];
    int    mreg[4];
#pragma unroll
    for (int i = 0; i < 4; ++i) {
        const int r = sr + i * 16;
        kreg[i] = *(const float4*)(K + base + (long)(s0 + r) * DDIM + sc);
        vreg[i] = *(const float4*)(V + base + (long)(s0 + r) * DDIM + sc);
        mreg[i] = mask[b * SDIM + s0 + r];
    }

    f32x4 acc[4];                          // et = w fixed; dt = 0..3
#pragma unroll
    for (int i = 0; i < 4; ++i) acc[i] = (f32x4){0.f, 0.f, 0.f, 0.f};
    f32x4 kacc = (f32x4){0.f, 0.f, 0.f, 0.f};   // ksum tile dt = w
    short8 ones;
#pragma unroll
    for (int j = 0; j < 8; ++j) ones[j] = (short)0x3F80;   // bf16 1.0

    for (int t = 0; t < 4; ++t) {          // 4 tiles of 64 s-rows
        __syncthreads();                   // prev tile's LDS fully consumed
#pragma unroll
        for (int i = 0; i < 4; ++i) {
            const int row = sr + i * 16;
            const int swz = ((row >> 3) & 3) << 4;
            const float m = mreg[i] ? 1.f : 0.f;
            float4 kq = kreg[i];
            kq.x = fmaxf(kq.x, 0.f) * m;
            kq.y = fmaxf(kq.y, 0.f) * m;
            kq.z = fmaxf(kq.z, 0.f) * m;
            kq.w = fmaxf(kq.w, 0.f) * m;
            *(float4*)(Ks + row * 64 + (sc ^ swz)) = kq;
            *(float4*)(Vs + row * 64 + (sc ^ swz)) = vreg[i];
        }
        __syncthreads();
        if (t < 3) {                       // prefetch next tile under compute
            const int r0n = s0 + (t + 1) * 64;
#pragma unroll
            for (int i = 0; i < 4; ++i) {
                const int r = sr + i * 16;
                kreg[i] = *(const float4*)(K + base + (long)(r0n + r) * DDIM + sc);
                vreg[i] = *(const float4*)(V + base + (long)(r0n + r) * DDIM + sc);
                mreg[i] = mask[b * SDIM + r0n + r];
            }
        }
        // compute tile t: k-steps kh=0,1 (32 s each)
#pragma unroll
        for (int kh = 0; kh < 2; ++kh) {
            const int sb = kh * 32 + quad * 8;
            const int qs = quad << 4;      // ((sb+j)>>3 & 3) << 4 == quad<<4
            short8 af[4];
#pragma unroll
            for (int dt = 0; dt < 4; ++dt) {
                short8 ta;
#pragma unroll
                for (int j = 0; j < 8; ++j)
                    ta[j] = f2bfs(Ks[(sb + j) * 64 + ((dt * 16 + r16) ^ qs)]);
                af[dt] = ta;
            }
            short8 bf;
#pragma unroll
            for (int j = 0; j < 8; ++j)
                bf[j] = f2bfs(Vs[(sb + j) * 64 + ((w * 16 + r16) ^ qs)]);
#pragma unroll
            for (int dt = 0; dt < 4; ++dt)
                acc[dt] = __builtin_amdgcn_mfma_f32_16x16x32_bf16(
                    af[dt], bf, acc[dt], 0, 0, 0);
            kacc = __builtin_amdgcn_mfma_f32_16x16x32_bf16(
                af[w], ones, kacc, 0, 0, 0);
        }
    }

    // ---- C-writeout via LDS bounce (coalesced 256B wave stores) ----
    __syncthreads();
#pragma unroll
    for (int dt = 0; dt < 4; ++dt)
#pragma unroll
        for (int r = 0; r < 4; ++r) {
            const int d = dt * 16 + quad * 4 + r;
            const int e = w * 16 + r16;
            Ks[d * 64 + (e ^ (((d >> 3) & 3) << 4))] = acc[dt][r];
        }
    // ksum rows w*16..w*16+15 into Vs[0..63]
    if (r16 == 0) {
#pragma unroll
        for (int r = 0; r < 4; ++r)
            Vs[w * 16 + quad * 4 + r] = kacc[r];
    }
    __syncthreads();
    float* outp = KVp + ((long)bh * NC + ch) * 4096;
#pragma unroll
    for (int i = 0; i < 16; ++i) {
        const int idx = i * 256 + tid;
        const int d = idx >> 6, e = idx & 63;
        outp[idx] = Ks[d * 64 + (e ^ (((d >> 3) & 3) << 4))];
    }
    if (tid < 64)
        ksump[((long)bh * NC + ch) * 64 + tid] = Vs[tid];
}

// ---------------------------------------------------------------------------
// k2: reduce NC chunk partials -> final KV, ksum. (unchanged)
// ---------------------------------------------------------------------------
__global__ __launch_bounds__(256) void k2_reduce(
    const float* __restrict__ KVp, const float* __restrict__ ksump,
    float* __restrict__ KV, float* __restrict__ ksum)
{
    const int bh = blockIdx.x >> 2;
    const int qt = blockIdx.x & 3;
    const int tid = threadIdx.x;
#pragma unroll
    for (int i = 0; i < 4; ++i) {
        const int idx = qt * 1024 + i * 256 + tid;
        float v = 0.f;
#pragma unroll
        for (int c = 0; c < NC; ++c) v += KVp[((long)bh * NC + c) * 4096 + idx];
        KV[(long)bh * 4096 + idx] = v;
    }
    if (qt == 0 && tid < 64) {
        float v = 0.f;
#pragma unroll
        for (int c = 0; c < NC; ++c) v += ksump[((long)bh * NC + c) * 64 + tid];
        ksum[bh * 64 + tid] = v;
    }
}

// ---------------------------------------------------------------------------
// k3 v4 (MFMA): out = (relu(Q) @ KV_bf16) * (1/norm), norm fp32. (unchanged)
// ---------------------------------------------------------------------------
__global__ __launch_bounds__(256, 4) void k3_out(
    const float* __restrict__ Q, const float* __restrict__ KVm,
    const float* __restrict__ ksum, float* __restrict__ out)
{
    __shared__ float cbuf[4][16 * 68];     // 17.4 KB, per-wave strips
    const int tid  = threadIdx.x;
    const int w    = tid >> 6;
    const int l    = tid & 63;
    const int r16  = l & 15;
    const int quad = l >> 4;
    const int bh    = blockIdx.x >> 4;
    const int strip = blockIdx.x & 15;     // 16 strips x 256 rows

    const float* kvp = KVm + (long)bh * 4096;
    short8 bfrag[2][4];
#pragma unroll
    for (int kh = 0; kh < 2; ++kh)
#pragma unroll
        for (int n = 0; n < 4; ++n) {
            short8 tmp;
#pragma unroll
            for (int j = 0; j < 8; ++j)
                tmp[j] = f2bfs(kvp[(kh * 32 + quad * 8 + j) * 64 + n * 16 + r16]);
            bfrag[kh][n] = tmp;
        }
    float ksv[16];
#pragma unroll
    for (int j = 0; j < 8; ++j) {
        ksv[j]     = ksum[bh * 64 + quad * 8 + j];
        ksv[j + 8] = ksum[bh * 64 + 32 + quad * 8 + j];
    }

    const int rowbase = strip * 256 + w * 64;
    const float* qptr = Q + ((long)bh * SDIM + rowbase + r16) * DDIM + quad * 8;
    float* obase = out + ((long)bh * SDIM + rowbase) * DDIM;
    float* cw = &cbuf[w][0];

    f32x4 a0 = *(const f32x4*)(qptr);
    f32x4 a1 = *(const f32x4*)(qptr + 4);
    f32x4 a2 = *(const f32x4*)(qptr + 32);
    f32x4 a3 = *(const f32x4*)(qptr + 36);

    for (int t = 0; t < 4; ++t) {
        f32x4 b0 = a0, b1 = a1, b2 = a2, b3 = a3;
        if (t < 3) {
            const float* qn = qptr + (t + 1) * 16 * DDIM;
            b0 = *(const f32x4*)(qn);
            b1 = *(const f32x4*)(qn + 4);
            b2 = *(const f32x4*)(qn + 32);
            b3 = *(const f32x4*)(qn + 36);
        }
#pragma unroll
        for (int j = 0; j < 4; ++j) {
            a0[j] = fmaxf(a0[j], 0.f); a1[j] = fmaxf(a1[j], 0.f);
            a2[j] = fmaxf(a2[j], 0.f); a3[j] = fmaxf(a3[j], 0.f);
        }
        float p = 0.f;
#pragma unroll
        for (int j = 0; j < 4; ++j) {
            p = fmaf(a0[j], ksv[j],      p);
            p = fmaf(a1[j], ksv[4 + j],  p);
            p = fmaf(a2[j], ksv[8 + j],  p);
            p = fmaf(a3[j], ksv[12 + j], p);
        }
        p += __shfl_xor(p, 16);
        p += __shfl_xor(p, 32);
        const float inv = __builtin_amdgcn_rcpf(p);

        short8 af0, af1;
#pragma unroll
        for (int j = 0; j < 4; ++j) {
            af0[j]     = f2bfs(a0[j]);
            af0[4 + j] = f2bfs(a1[j]);
            af1[j]     = f2bfs(a2[j]);
            af1[4 + j] = f2bfs(a3[j]);
        }

        f32x4 acc[4];
#pragma unroll
        for (int n = 0; n < 4; ++n) {
            acc[n] = (f32x4){0.f, 0.f, 0.f, 0.f};
            acc[n] = __builtin_amdgcn_mfma_f32_16x16x32_bf16(af0, bfrag[0][n], acc[n], 0, 0, 0);
            acc[n] = __builtin_amdgcn_mfma_f32_16x16x32_bf16(af1, bfrag[1][n], acc[n], 0, 0, 0);
        }

        float invr[4];
#pragma unroll
        for (int r = 0; r < 4; ++r) invr[r] = __shfl(inv, quad * 4 + r);

#pragma unroll
        for (int n = 0; n < 4; ++n)
#pragma unroll
            for (int r = 0; r < 4; ++r)
                cw[(quad * 4 + r) * 68 + n * 16 + r16] = acc[n][r] * invr[r];

        float* ot = obase + (t * 16) * DDIM;
#pragma unroll
        for (int i = 0; i < 4; ++i) {
            f32x4 v = *(const f32x4*)(cw + (i * 4 + quad) * 68 + r16 * 4);
            *(f32x4*)(ot + (i * 4 + quad) * DDIM + r16 * 4) = v;
        }
        a0 = b0; a1 = b1; a2 = b2; a3 = b3;
    }
}

extern "C" void kernel_launch(void* const* d_in, const int* in_sizes, int n_in,
                              void* d_out, int out_size, void* d_ws, size_t ws_size,
                              hipStream_t stream)
{
    const float* Q    = (const float*)d_in[0];
    const float* K    = (const float*)d_in[1];
    const float* V    = (const float*)d_in[2];
    const int*   mask = (const int*)d_in[3];
    float* out = (float*)d_out;

    // Chunk partials live in d_out (scratch; k3 overwrites all of d_out).
    float* KVp   = out;                                // 16.8 MB scratch
    float* ksump = KVp + (long)BH * NC * 4096;         // 256 KB
    float* KV    = (float*)d_ws;                       // 1 MB
    float* ksum  = KV + (long)BH * 4096;               // 16 KB

    hipLaunchKernelGGL(k1_kv, dim3(BH * NC), dim3(256), 0, stream,
                       K, V, mask, KVp, ksump);
    hipLaunchKernelGGL(k2_reduce, dim3(BH * 4), dim3(256), 0, stream,
                       KVp, ksump, KV, ksum);
    hipLaunchKernelGGL(k3_out, dim3(BH * 16), dim3(256), 0, stream,
                       Q, KV, ksum, out);
}

// Round 11
// 62.511 us; speedup vs baseline: 1.5692x; 1.4183x over previous
//
#include <hip/hip_runtime.h>
#include <hip/hip_bf16.h>

#define SDIM 4096
#define DDIM 64
#define HN   16
#define BH   64
#define NC   16

typedef __attribute__((ext_vector_type(8))) short short8;
typedef __attribute__((ext_vector_type(4))) float f32x4;

static __device__ __forceinline__ short f2bfs(float f) {
    __hip_bfloat16 h = __float2bfloat16(f);      // HW RNE cvt (pk-fusable)
    return *reinterpret_cast<short*>(&h);
}

// ---------------------------------------------------------------------------
// k1 v8: per (bh, 256-row chunk) partial KV[64][64] + ksum[64].
//  - Direct-global fragment gather: per 32-row step each lane issues 40
//    independent dword loads, all compile-time imm offsets from one per-lane
//    base -> burst in flight, latency hidden by TLP. No barriers in loop.
//  - e-split across waves: wave w owns e-cols w*16..+15 -> acc = 4 f32x4.
//  - ksum via fp32 VALU accumulation folded into the relu/mask fragment
//    build (NO guarded MFMA -- exec-masked MFMA is undefined on CDNA and
//    was the NaN source in rounds 9/10). All waves compute identical K-side
//    sums; shfl_xor reduce over lane-quads; wave 0 writes.
//  - Writeout via validated LDS bounce (256B-contiguous stores).
// ---------------------------------------------------------------------------
__global__ __launch_bounds__(256, 4) void k1_kv(
    const float* __restrict__ K, const float* __restrict__ V,
    const int* __restrict__ mask,
    float* __restrict__ KVp, float* __restrict__ ksump)
{
    __shared__ float kb[4096];             // 16 KB bounce
    const int tid = threadIdx.x;
    const int w = tid >> 6, l = tid & 63;
    const int a = l & 15, q = l >> 4;
    const int bh = blockIdx.x >> 4, ch = blockIdx.x & 15;
    const int b  = bh >> 4;                // bh / HN
    const long base = (long)bh * SDIM * DDIM;
    const int s0 = ch * 256;

    f32x4 acc[4];                          // d-tiles 0..3, e-slice = w
#pragma unroll
    for (int i = 0; i < 4; ++i) acc[i] = (f32x4){0.f, 0.f, 0.f, 0.f};
    float ksacc[4] = {0.f, 0.f, 0.f, 0.f}; // fp32 row-sum partials (per dt)

    for (int st = 0; st < 8; ++st) {       // 8 steps of 32 s-rows
        const int sb = st * 32;
        // per-lane bases; all loads below are imm-offset from these
        const float* kp = K + base + (long)(s0 + sb + q * 8) * DDIM + a;
        const float* vp = V + base + (long)(s0 + sb + q * 8) * DDIM + w * 16 + a;
        const int*   mp = mask + b * SDIM + s0 + sb + q * 8;

        float kf[4][8], vf[8];
        int   mi[8];
#pragma unroll
        for (int j = 0; j < 8; ++j) {      // 40 + 8 loads, one burst
            mi[j] = mp[j];
#pragma unroll
            for (int dt = 0; dt < 4; ++dt)
                kf[dt][j] = kp[j * 64 + dt * 16];
            vf[j] = vp[j * 64];
        }

        short8 af[4], bf;
#pragma unroll
        for (int dt = 0; dt < 4; ++dt) {
            short8 ta;
#pragma unroll
            for (int j = 0; j < 8; ++j) {
                float x = fmaxf(kf[dt][j], 0.f);
                x = mi[j] ? x : 0.f;
                ksacc[dt] += x;            // fp32 ksum partial (free VALU)
                ta[j] = f2bfs(x);
            }
            af[dt] = ta;
        }
#pragma unroll
        for (int j = 0; j < 8; ++j) bf[j] = f2bfs(vf[j]);

#pragma unroll
        for (int dt = 0; dt < 4; ++dt)
            acc[dt] = __builtin_amdgcn_mfma_f32_16x16x32_bf16(
                af[dt], bf, acc[dt], 0, 0, 0);
    }

    // ---- ksum: reduce over lane-quads (s-slices), wave 0 writes ----
#pragma unroll
    for (int dt = 0; dt < 4; ++dt) {
        ksacc[dt] += __shfl_xor(ksacc[dt], 16);
        ksacc[dt] += __shfl_xor(ksacc[dt], 32);
    }
    if (w == 0 && q == 0) {                // lanes 0..15
#pragma unroll
        for (int dt = 0; dt < 4; ++dt)
            ksump[((long)bh * NC + ch) * 64 + dt * 16 + a] = ksacc[dt];
    }

    // ---- KV writeout via LDS bounce (validated path) ----
    __syncthreads();
#pragma unroll
    for (int dt = 0; dt < 4; ++dt)
#pragma unroll
        for (int r = 0; r < 4; ++r) {
            const int d = dt * 16 + q * 4 + r;
            const int e = w * 16 + a;
            kb[d * 64 + (e ^ (((d >> 3) & 3) << 4))] = acc[dt][r];
        }
    __syncthreads();
    float* outp = KVp + ((long)bh * NC + ch) * 4096;
#pragma unroll
    for (int i = 0; i < 16; ++i) {
        const int idx = i * 256 + tid;
        const int d = idx >> 6, e = idx & 63;
        outp[idx] = kb[d * 64 + (e ^ (((d >> 3) & 3) << 4))];
    }
}

// ---------------------------------------------------------------------------
// k2: reduce NC chunk partials -> final KV, ksum. (unchanged, validated)
// ---------------------------------------------------------------------------
__global__ __launch_bounds__(256) void k2_reduce(
    const float* __restrict__ KVp, const float* __restrict__ ksump,
    float* __restrict__ KV, float* __restrict__ ksum)
{
    const int bh = blockIdx.x >> 2;
    const int qt = blockIdx.x & 3;
    const int tid = threadIdx.x;
#pragma unroll
    for (int i = 0; i < 4; ++i) {
        const int idx = qt * 1024 + i * 256 + tid;
        float v = 0.f;
#pragma unroll
        for (int c = 0; c < NC; ++c) v += KVp[((long)bh * NC + c) * 4096 + idx];
        KV[(long)bh * 4096 + idx] = v;
    }
    if (qt == 0 && tid < 64) {
        float v = 0.f;
#pragma unroll
        for (int c = 0; c < NC; ++c) v += ksump[((long)bh * NC + c) * 64 + tid];
        ksum[bh * 64 + tid] = v;
    }
}

// ---------------------------------------------------------------------------
// k3 v4 (MFMA): out = (relu(Q) @ KV_bf16) * (1/norm), norm fp32.
// (unchanged, validated)
// ---------------------------------------------------------------------------
__global__ __launch_bounds__(256, 4) void k3_out(
    const float* __restrict__ Q, const float* __restrict__ KVm,
    const float* __restrict__ ksum, float* __restrict__ out)
{
    __shared__ float cbuf[4][16 * 68];     // 17.4 KB, per-wave strips
    const int tid  = threadIdx.x;
    const int w    = tid >> 6;
    const int l    = tid & 63;
    const int r16  = l & 15;
    const int quad = l >> 4;
    const int bh    = blockIdx.x >> 4;
    const int strip = blockIdx.x & 15;     // 16 strips x 256 rows

    const float* kvp = KVm + (long)bh * 4096;
    short8 bfrag[2][4];
#pragma unroll
    for (int kh = 0; kh < 2; ++kh)
#pragma unroll
        for (int n = 0; n < 4; ++n) {
            short8 tmp;
#pragma unroll
            for (int j = 0; j < 8; ++j)
                tmp[j] = f2bfs(kvp[(kh * 32 + quad * 8 + j) * 64 + n * 16 + r16]);
            bfrag[kh][n] = tmp;
        }
    float ksv[16];
#pragma unroll
    for (int j = 0; j < 8; ++j) {
        ksv[j]     = ksum[bh * 64 + quad * 8 + j];
        ksv[j + 8] = ksum[bh * 64 + 32 + quad * 8 + j];
    }

    const int rowbase = strip * 256 + w * 64;
    const float* qptr = Q + ((long)bh * SDIM + rowbase + r16) * DDIM + quad * 8;
    float* obase = out + ((long)bh * SDIM + rowbase) * DDIM;
    float* cw = &cbuf[w][0];

    f32x4 a0 = *(const f32x4*)(qptr);
    f32x4 a1 = *(const f32x4*)(qptr + 4);
    f32x4 a2 = *(const f32x4*)(qptr + 32);
    f32x4 a3 = *(const f32x4*)(qptr + 36);

    for (int t = 0; t < 4; ++t) {
        f32x4 b0 = a0, b1 = a1, b2 = a2, b3 = a3;
        if (t < 3) {
            const float* qn = qptr + (t + 1) * 16 * DDIM;
            b0 = *(const f32x4*)(qn);
            b1 = *(const f32x4*)(qn + 4);
            b2 = *(const f32x4*)(qn + 32);
            b3 = *(const f32x4*)(qn + 36);
        }
#pragma unroll
        for (int j = 0; j < 4; ++j) {
            a0[j] = fmaxf(a0[j], 0.f); a1[j] = fmaxf(a1[j], 0.f);
            a2[j] = fmaxf(a2[j], 0.f); a3[j] = fmaxf(a3[j], 0.f);
        }
        float p = 0.f;
#pragma unroll
        for (int j = 0; j < 4; ++j) {
            p = fmaf(a0[j], ksv[j],      p);
            p = fmaf(a1[j], ksv[4 + j],  p);
            p = fmaf(a2[j], ksv[8 + j],  p);
            p = fmaf(a3[j], ksv[12 + j], p);
        }
        p += __shfl_xor(p, 16);
        p += __shfl_xor(p, 32);
        const float inv = __builtin_amdgcn_rcpf(p);

        short8 af0, af1;
#pragma unroll
        for (int j = 0; j < 4; ++j) {
            af0[j]     = f2bfs(a0[j]);
            af0[4 + j] = f2bfs(a1[j]);
            af1[j]     = f2bfs(a2[j]);
            af1[4 + j] = f2bfs(a3[j]);
        }

        f32x4 acc[4];
#pragma unroll
        for (int n = 0; n < 4; ++n) {
            acc[n] = (f32x4){0.f, 0.f, 0.f, 0.f};
            acc[n] = __builtin_amdgcn_mfma_f32_16x16x32_bf16(af0, bfrag[0][n], acc[n], 0, 0, 0);
            acc[n] = __builtin_amdgcn_mfma_f32_16x16x32_bf16(af1, bfrag[1][n], acc[n], 0, 0, 0);
        }

        float invr[4];
#pragma unroll
        for (int r = 0; r < 4; ++r) invr[r] = __shfl(inv, quad * 4 + r);

#pragma unroll
        for (int n = 0; n < 4; ++n)
#pragma unroll
            for (int r = 0; r < 4; ++r)
                cw[(quad * 4 + r) * 68 + n * 16 + r16] = acc[n][r] * invr[r];

        float* ot = obase + (t * 16) * DDIM;
#pragma unroll
        for (int i = 0; i < 4; ++i) {
            f32x4 v = *(const f32x4*)(cw + (i * 4 + quad) * 68 + r16 * 4);
            *(f32x4*)(ot + (i * 4 + quad) * DDIM + r16 * 4) = v;
        }
        a0 = b0; a1 = b1; a2 = b2; a3 = b3;
    }
}

extern "C" void kernel_launch(void* const* d_in, const int* in_sizes, int n_in,
                              void* d_out, int out_size, void* d_ws, size_t ws_size,
                              hipStream_t stream)
{
    const float* Q    = (const float*)d_in[0];
    const float* K    = (const float*)d_in[1];
    const float* V    = (const float*)d_in[2];
    const int*   mask = (const int*)d_in[3];
    float* out = (float*)d_out;

    // Chunk partials live in d_out (scratch; k3 overwrites all of d_out).
    float* KVp   = out;                                // 16.8 MB scratch
    float* ksump = KVp + (long)BH * NC * 4096;         // 256 KB
    float* KV    = (float*)d_ws;                       // 1 MB
    float* ksum  = KV + (long)BH * 4096;               // 16 KB

    hipLaunchKernelGGL(k1_kv, dim3(BH * NC), dim3(256), 0, stream,
                       K, V, mask, KVp, ksump);
    hipLaunchKernelGGL(k2_reduce, dim3(BH * 4), dim3(256), 0, stream,
                       KVp, ksump, KV, ksum);
    hipLaunchKernelGGL(k3_out, dim3(BH * 16), dim3(256), 0, stream,
                       Q, KV, ksum, out);
}